// Round 7
// baseline (274.188 us; speedup 1.0000x reference)
//
#include <hip/hip_runtime.h>

// Depthwise 5x5 SAME conv + gate residual: out = x*(alpha*conv + bias) + x
// x: (B=32, H=112, W=112, C=96) f32 NHWC. kernel: (5,5,96) f32.
//
// R7 = R6 with the consume/reload order bug fixed:
//  - Each body SNAPSHOTS the buffer loaded 3 bodies ago (t0..t4, register
//    renames), THEN reissues the buffer's loads for row h0+1+i, then
//    sched_barrier(0) pins those loads above the FMAs (compiler was
//    sinking them -> prefetch depth 0 -> 26% VALU duty, latency-bound).
//  - Depth-3 ring (ta/tb/tc); row r consumed at body r-(h0-2), reloaded
//    for r+3.
//  - __launch_bounds__(256,4): VGPR cap 128 for the honest live set.
//  - float2 lanes, clamped tap offsets + weight-zeroing for W edges,
//    NSPLIT=3 (98.4% wave-slot packing).

#define CH     96
#define C2     48                  // float2 channel-pairs per position
#define WI     112
#define HI     112
#define BATCH  32
#define NSPLIT 3
#define CHUNK_ROWS 38              // chunks: 38, 38, 36 (nit 42/42/40)
#define ROW_F2 (WI * C2)           // float2 per image row = 5376
#define IMG_F2 (HI * ROW_F2)

__global__ __launch_bounds__(256, 4) void dwconv_gate_kernel(
    const float* __restrict__ x,
    const float* __restrict__ kern,
    const float* __restrict__ alpha,
    const float* __restrict__ bias,
    float* __restrict__ out)
{
    const int gid = blockIdx.x * blockDim.x + threadIdx.x;
    // gid -> (b, chunk, w, c2); c2 innermost for coalescing
    const int c2    = gid % C2;
    const int r1    = gid / C2;
    const int w     = r1 % WI;
    const int r2    = r1 / WI;
    const int chunk = r2 % NSPLIT;
    const int b     = r2 / NSPLIT;
    if (b >= BATCH) return;

    const float alphav = alpha[0];
    const float biasv  = bias[0];

    // Clamped tap offsets (float2 units); OOB contributions killed by
    // zeroed weights, so interior loads need no masks at all.
    int toff[5];
    bool mok[5];
#pragma unroll
    for (int dx = 0; dx < 5; ++dx) {
        const int ww = w + dx - 2;
        mok[dx] = (ww >= 0) && (ww < WI);
        const int wc = ww < 0 ? 0 : (ww >= WI ? WI - 1 : ww);
        toff[dx] = (wc - w) * C2;
    }

    float2 wt[25];
#pragma unroll
    for (int i = 0; i < 25; ++i) {
        float2 v = *(const float2*)(kern + i * CH + 2 * c2);
        if (!mok[i % 5]) v = make_float2(0.f, 0.f);
        wt[i] = v;
    }

    const int h0   = chunk * CHUNK_ROWS;
    const int rows = (chunk == NSPLIT - 1) ? (HI - h0) : CHUNK_ROWS;
    const int nit  = rows + 4;     // 42 / 42 / 40  (nit % 3 is 0 or 1)

    const float2* px = (const float2*)x   + (size_t)b * IMG_F2 + (size_t)w * C2 + c2;
    float2*       po = (float2*)      out + (size_t)b * IMG_F2 + (size_t)w * C2 + c2;

    float2 acc0 = make_float2(0.f, 0.f), acc1 = acc0, acc2 = acc0,
           acc3 = acc0, acc4 = acc0;
    float2 xp1 = acc0, xp2 = acc0;   // center-tap history (delay 2)
    float2 ta[5], tb[5], tc[5];

    // Row load into BUF. Row index is block-uniform -> uniform branch.
#define LOADROW(BUF, RIN) do {                                             \
        const int _r = (RIN);                                              \
        if ((unsigned)_r < (unsigned)HI) {                                 \
            const float2* _p = px + (ptrdiff_t)_r * ROW_F2;                \
            BUF[0] = _p[toff[0]];                                          \
            BUF[1] = _p[toff[1]];                                          \
            BUF[2] = _p[toff[2]];                                          \
            BUF[3] = _p[toff[3]];                                          \
            BUF[4] = _p[toff[4]];                                          \
        } else {                                                           \
            BUF[0] = make_float2(0.f, 0.f);                                \
            BUF[1] = make_float2(0.f, 0.f);                                \
            BUF[2] = make_float2(0.f, 0.f);                                \
            BUF[3] = make_float2(0.f, 0.f);                                \
            BUF[4] = make_float2(0.f, 0.f);                                \
        }                                                                  \
    } while (0)

    // Prologue: 15 tap loads (3 rows) in flight before the first consume.
    LOADROW(ta, h0 - 2);
    LOADROW(tb, h0 - 1);
    LOADROW(tc, h0    );

    // Body _i:
    //   1. snapshot T (holds input row h0-2+_i, loaded 3 bodies ago)
    //   2. reissue T's loads for row h0+1+_i (consumed 3 bodies later)
    //   3. sched_barrier(0) -- the loads may not sink past this point
    //   4. 50 FMAs on the snapshot; emit output row h0-4+_i when complete
#define BODY(I, T) do {                                                    \
        const int _i = (I);                                                \
        float2 t0 = T[0], t1 = T[1], t2 = T[2], t3 = T[3], t4 = T[4];      \
        LOADROW(T, h0 + 1 + _i);                                           \
        __builtin_amdgcn_sched_barrier(0);                                 \
        acc0.x = fmaf(t0.x, wt[20].x, acc0.x);                             \
        acc0.y = fmaf(t0.y, wt[20].y, acc0.y);                             \
        acc0.x = fmaf(t1.x, wt[21].x, acc0.x);                             \
        acc0.y = fmaf(t1.y, wt[21].y, acc0.y);                             \
        acc0.x = fmaf(t2.x, wt[22].x, acc0.x);                             \
        acc0.y = fmaf(t2.y, wt[22].y, acc0.y);                             \
        acc0.x = fmaf(t3.x, wt[23].x, acc0.x);                             \
        acc0.y = fmaf(t3.y, wt[23].y, acc0.y);                             \
        acc0.x = fmaf(t4.x, wt[24].x, acc0.x);                             \
        acc0.y = fmaf(t4.y, wt[24].y, acc0.y);                             \
        acc1.x = fmaf(t0.x, wt[15].x, acc1.x);                             \
        acc1.y = fmaf(t0.y, wt[15].y, acc1.y);                             \
        acc1.x = fmaf(t1.x, wt[16].x, acc1.x);                             \
        acc1.y = fmaf(t1.y, wt[16].y, acc1.y);                             \
        acc1.x = fmaf(t2.x, wt[17].x, acc1.x);                             \
        acc1.y = fmaf(t2.y, wt[17].y, acc1.y);                             \
        acc1.x = fmaf(t3.x, wt[18].x, acc1.x);                             \
        acc1.y = fmaf(t3.y, wt[18].y, acc1.y);                             \
        acc1.x = fmaf(t4.x, wt[19].x, acc1.x);                             \
        acc1.y = fmaf(t4.y, wt[19].y, acc1.y);                             \
        acc2.x = fmaf(t0.x, wt[10].x, acc2.x);                             \
        acc2.y = fmaf(t0.y, wt[10].y, acc2.y);                             \
        acc2.x = fmaf(t1.x, wt[11].x, acc2.x);                             \
        acc2.y = fmaf(t1.y, wt[11].y, acc2.y);                             \
        acc2.x = fmaf(t2.x, wt[12].x, acc2.x);                             \
        acc2.y = fmaf(t2.y, wt[12].y, acc2.y);                             \
        acc2.x = fmaf(t3.x, wt[13].x, acc2.x);                             \
        acc2.y = fmaf(t3.y, wt[13].y, acc2.y);                             \
        acc2.x = fmaf(t4.x, wt[14].x, acc2.x);                             \
        acc2.y = fmaf(t4.y, wt[14].y, acc2.y);                             \
        acc3.x = fmaf(t0.x, wt[ 5].x, acc3.x);                             \
        acc3.y = fmaf(t0.y, wt[ 5].y, acc3.y);                             \
        acc3.x = fmaf(t1.x, wt[ 6].x, acc3.x);                             \
        acc3.y = fmaf(t1.y, wt[ 6].y, acc3.y);                             \
        acc3.x = fmaf(t2.x, wt[ 7].x, acc3.x);                             \
        acc3.y = fmaf(t2.y, wt[ 7].y, acc3.y);                             \
        acc3.x = fmaf(t3.x, wt[ 8].x, acc3.x);                             \
        acc3.y = fmaf(t3.y, wt[ 8].y, acc3.y);                             \
        acc3.x = fmaf(t4.x, wt[ 9].x, acc3.x);                             \
        acc3.y = fmaf(t4.y, wt[ 9].y, acc3.y);                             \
        acc4.x = fmaf(t0.x, wt[ 0].x, acc4.x);                             \
        acc4.y = fmaf(t0.y, wt[ 0].y, acc4.y);                             \
        acc4.x = fmaf(t1.x, wt[ 1].x, acc4.x);                             \
        acc4.y = fmaf(t1.y, wt[ 1].y, acc4.y);                             \
        acc4.x = fmaf(t2.x, wt[ 2].x, acc4.x);                             \
        acc4.y = fmaf(t2.y, wt[ 2].y, acc4.y);                             \
        acc4.x = fmaf(t3.x, wt[ 3].x, acc4.x);                             \
        acc4.y = fmaf(t3.y, wt[ 3].y, acc4.y);                             \
        acc4.x = fmaf(t4.x, wt[ 4].x, acc4.x);                             \
        acc4.y = fmaf(t4.y, wt[ 4].y, acc4.y);                             \
        if (_i >= 4) {                                                     \
            float2 o;                                                      \
            o.x = fmaf(fmaf(acc0.x, alphav, biasv), xp2.x, xp2.x);         \
            o.y = fmaf(fmaf(acc0.y, alphav, biasv), xp2.y, xp2.y);         \
            po[(ptrdiff_t)(h0 - 4 + _i) * ROW_F2] = o;                     \
        }                                                                  \
        xp2 = xp1; xp1 = t2;                                               \
        acc0 = acc1; acc1 = acc2; acc2 = acc3; acc3 = acc4;                \
        acc4 = make_float2(0.f, 0.f);                                      \
    } while (0)

    int i = 0;
    for (; i + 3 <= nit; i += 3) {
        BODY(i + 0, ta);
        BODY(i + 1, tb);
        BODY(i + 2, tc);
    }
    if (i < nit) BODY(i, ta);      // nit % 3 is 0 or 1, never 2
#undef BODY
#undef LOADROW
}

extern "C" void kernel_launch(void* const* d_in, const int* in_sizes, int n_in,
                              void* d_out, int out_size, void* d_ws, size_t ws_size,
                              hipStream_t stream) {
    const float* x     = (const float*)d_in[0];
    const float* kern  = (const float*)d_in[1];
    const float* alpha = (const float*)d_in[2];
    const float* bias  = (const float*)d_in[3];
    float* out = (float*)d_out;

    const int total = BATCH * NSPLIT * WI * C2;   // 516,096 = 2016 * 256
    dim3 block(256);
    dim3 grid(total / 256);                       // 2016 blocks, 8064 waves
    hipLaunchKernelGGL(dwconv_gate_kernel, grid, block, 0, stream,
                       x, kern, alpha, bias, out);
}

// Round 8
// 112.617 us; speedup vs baseline: 2.4347x; 2.4347x over previous
//
#include <hip/hip_runtime.h>

// Depthwise 5x5 SAME conv + gate residual: out = x*(alpha*conv + bias) + x
// x: (B=32, H=112, W=112, C=96) f32 NHWC. kernel: (5,5,96) f32.
//
// R8: block-cooperative LDS row staging (the Sec.5/T14 pattern), replacing
// per-thread global tap loads whose prefetch the compiler kept defeating
// (R4/R6/R7 all spilled or sank to depth 0; duration pinned ~125us).
//  - Block tile: (b, 16-w segment, 16-h chunk, all 96 ch). 384 threads.
//  - Per input row: ONE contiguous 7680 B burst (global->regs, coalesced)
//    issued at body top; consumed by ds_write AFTER compute + barrier
//    (T14 issue-early/write-late) -> HBM latency hides under 200+ cyc FMA.
//  - Taps from LDS (2-slot ring, one barrier per row). All LDS ops are
//    consecutive-512B-per-wave -> conflict-free.
//  - Thread owns one c2 channel-pair at w and w+8: weights = 25 f2 = 50
//    VGPR, reused for both outputs. acc ring 5x2 f2, statically indexed.

#define CHN   96
#define C2    48                 // float2 channel pairs
#define WI    112
#define HI    112
#define NB    32
#define WSEG  16                 // output w per block
#define LW    20                 // staged w per row (WSEG + 4 halo)
#define ROWF2 (LW * C2)          // 960 f2 = 7680 B per staged row
#define HCH   16                 // output rows per block (7*16 = 112)
#define NHC   7
#define NWC   7
#define NTHR  384                // 6 waves; 48 c2 x 8 wsub
#define GROW  (WI * C2)          // 5376 f2 per (b,h) row
#define GIMG  (HI * GROW)

__global__ __launch_bounds__(NTHR, 4) void dwconv_gate_lds(
    const float* __restrict__ xf,
    const float* __restrict__ kf,
    const float* __restrict__ alpha,
    const float* __restrict__ bias,
    float* __restrict__ of)
{
    __shared__ float2 sA[ROWF2];
    __shared__ float2 sB[ROWF2];

    const int tid  = threadIdx.x;
    const int bid  = blockIdx.x;
    const int wseg = bid % NWC;
    const int hch  = (bid / NWC) % NHC;
    const int b    = bid / (NWC * NHC);

    const int c2l  = tid % C2;
    const int wsub = tid / C2;          // 0..7
    const int w0   = wseg * WSEG;
    const int h0   = hch * HCH;

    const float av = alpha[0];
    const float bv = bias[0];
    const float2 z2 = make_float2(0.f, 0.f);

    // Per-channel-pair 5x5 weights (static indices -> registers).
    float2 wt[25];
#pragma unroll
    for (int i = 0; i < 25; ++i)
        wt[i] = *(const float2*)(kf + i * CHN + 2 * c2l);

    // Staging: row tile = LW*C2 f2, covered as k = tid, tid+384, tid+768
    // (tid<192). k -> (wl = k/C2, c2 = k%C2); wglob = w0-2+wl.
    const int wg0 = w0 - 2 + wsub;       // wl = wsub
    const int wg1 = wg0 + 8;             // wl = wsub + 8
    const int wg2 = wg0 + 16;            // wl = wsub + 16 (tid<192 only)
    const bool okw0 = ((unsigned)wg0 < (unsigned)WI);
    const bool okw1 = ((unsigned)wg1 < (unsigned)WI);
    const bool okw2 = (tid < 192) && ((unsigned)wg2 < (unsigned)WI);
    const int co0 = okw0 ? (wg0 * C2 + c2l) : 0;   // clamped: always in-bounds
    const int co1 = okw1 ? (wg1 * C2 + c2l) : 0;
    const int co2 = okw2 ? (wg2 * C2 + c2l) : 0;

    const float2* gx = (const float2*)xf + (size_t)b * GIMG;
    float2*       go = (float2*)of       + (size_t)b * GIMG;

    float2 s0, s1, s2;   // staged row (issue-early, write-late)

    // Load global row RL into s0..s2 (clamped addresses, masked values).
#define GLOAD(RL) do {                                                     \
        const int _rl = (RL);                                              \
        const bool _rok = ((unsigned)_rl < (unsigned)HI);                  \
        const float2* _p = gx + (size_t)(_rok ? _rl : 0) * GROW;           \
        float2 _v0 = _p[co0];                                              \
        float2 _v1 = _p[co1];                                              \
        float2 _v2 = _p[co2];                                              \
        s0 = (_rok && okw0) ? _v0 : z2;                                    \
        s1 = (_rok && okw1) ? _v1 : z2;                                    \
        s2 = (_rok && okw2) ? _v2 : z2;                                    \
    } while (0)

#define SWRITE(S) do {                                                     \
        S[tid]       = s0;                                                 \
        S[tid + 384] = s1;                                                 \
        if (tid < 192) S[tid + 768] = s2;  /* wave-uniform branch */       \
    } while (0)

    // Prologue: stage rows h0-2 -> A, h0-1 -> B.
    GLOAD(h0 - 2);
    SWRITE(sA);
    GLOAD(h0 - 1);
    SWRITE(sB);
    __syncthreads();

    float2 aA[5] = {z2, z2, z2, z2, z2};
    float2 aB[5] = {z2, z2, z2, z2, z2};
    float2 xA1 = z2, xA2 = z2, xB1 = z2, xB2 = z2;
    const int ba = wsub * C2 + c2l;      // LDS base for output w = w0+wsub

    // Body i: issue loads for row h0+i; consume input row h0-2+i from slot
    // S; emit output row h0-4+i (i>=4); barrier; ds_write staged row -> S.
    // Slot parity: row r lives in slot (r - (h0-2)) % 2 -> body i uses
    // sA when i even, sB when i odd. One barrier per body is sufficient:
    // writes to S (body i, post-barrier) vs reads of S (body i+2, after
    // body i+1's barrier) are ordered; lgkmcnt(0) precedes every s_barrier.
#define BODY(I, S) do {                                                    \
        const int _i = (I);                                                \
        GLOAD(h0 + _i);                                                    \
        float2 ta0 = S[ba];          float2 tb0 = S[ba + 8  * C2];         \
        float2 ta1 = S[ba + 1 * C2]; float2 tb1 = S[ba + 9  * C2];         \
        float2 ta2 = S[ba + 2 * C2]; float2 tb2 = S[ba + 10 * C2];         \
        float2 ta3 = S[ba + 3 * C2]; float2 tb3 = S[ba + 11 * C2];         \
        float2 ta4 = S[ba + 4 * C2]; float2 tb4 = S[ba + 12 * C2];         \
        _Pragma("unroll")                                                  \
        for (int j = 0; j < 5; ++j) {                                      \
            const int wb = (4 - j) * 5;                                    \
            aA[j].x = fmaf(ta0.x, wt[wb+0].x, aA[j].x);                    \
            aA[j].y = fmaf(ta0.y, wt[wb+0].y, aA[j].y);                    \
            aA[j].x = fmaf(ta1.x, wt[wb+1].x, aA[j].x);                    \
            aA[j].y = fmaf(ta1.y, wt[wb+1].y, aA[j].y);                    \
            aA[j].x = fmaf(ta2.x, wt[wb+2].x, aA[j].x);                    \
            aA[j].y = fmaf(ta2.y, wt[wb+2].y, aA[j].y);                    \
            aA[j].x = fmaf(ta3.x, wt[wb+3].x, aA[j].x);                    \
            aA[j].y = fmaf(ta3.y, wt[wb+3].y, aA[j].y);                    \
            aA[j].x = fmaf(ta4.x, wt[wb+4].x, aA[j].x);                    \
            aA[j].y = fmaf(ta4.y, wt[wb+4].y, aA[j].y);                    \
            aB[j].x = fmaf(tb0.x, wt[wb+0].x, aB[j].x);                    \
            aB[j].y = fmaf(tb0.y, wt[wb+0].y, aB[j].y);                    \
            aB[j].x = fmaf(tb1.x, wt[wb+1].x, aB[j].x);                    \
            aB[j].y = fmaf(tb1.y, wt[wb+1].y, aB[j].y);                    \
            aB[j].x = fmaf(tb2.x, wt[wb+2].x, aB[j].x);                    \
            aB[j].y = fmaf(tb2.y, wt[wb+2].y, aB[j].y);                    \
            aB[j].x = fmaf(tb3.x, wt[wb+3].x, aB[j].x);                    \
            aB[j].y = fmaf(tb3.y, wt[wb+3].y, aB[j].y);                    \
            aB[j].x = fmaf(tb4.x, wt[wb+4].x, aB[j].x);                    \
            aB[j].y = fmaf(tb4.y, wt[wb+4].y, aB[j].y);                    \
        }                                                                  \
        if (_i >= 4) {                                                     \
            const int _ro = h0 - 4 + _i;                                   \
            float2 oa, ob;                                                 \
            oa.x = fmaf(fmaf(aA[0].x, av, bv), xA2.x, xA2.x);              \
            oa.y = fmaf(fmaf(aA[0].y, av, bv), xA2.y, xA2.y);              \
            ob.x = fmaf(fmaf(aB[0].x, av, bv), xB2.x, xB2.x);              \
            ob.y = fmaf(fmaf(aB[0].y, av, bv), xB2.y, xB2.y);              \
            float2* _q = go + (size_t)_ro * GROW + (w0 + wsub) * C2 + c2l; \
            _q[0]      = oa;                                               \
            _q[8 * C2] = ob;                                               \
        }                                                                  \
        xA2 = xA1; xA1 = ta2;                                              \
        xB2 = xB1; xB1 = tb2;                                              \
        aA[0] = aA[1]; aA[1] = aA[2]; aA[2] = aA[3]; aA[3] = aA[4];        \
        aA[4] = z2;                                                        \
        aB[0] = aB[1]; aB[1] = aB[2]; aB[2] = aB[3]; aB[3] = aB[4];        \
        aB[4] = z2;                                                        \
        __syncthreads();                                                   \
        SWRITE(S);                                                         \
    } while (0)

    for (int m = 0; m < HCH + 4; m += 2) {   // 20 bodies, slots A/B
        BODY(m,     sA);
        BODY(m + 1, sB);
    }
#undef BODY
#undef SWRITE
#undef GLOAD
}

extern "C" void kernel_launch(void* const* d_in, const int* in_sizes, int n_in,
                              void* d_out, int out_size, void* d_ws, size_t ws_size,
                              hipStream_t stream) {
    const float* x     = (const float*)d_in[0];
    const float* kern  = (const float*)d_in[1];
    const float* alpha = (const float*)d_in[2];
    const float* bias  = (const float*)d_in[3];
    float* out = (float*)d_out;

    dim3 block(NTHR);
    dim3 grid(NB * NHC * NWC);            // 32*7*7 = 1568 blocks
    hipLaunchKernelGGL(dwconv_gate_lds, grid, block, 0, stream,
                       x, kern, alpha, bias, out);
}

// Round 9
// 110.356 us; speedup vs baseline: 2.4846x; 1.0205x over previous
//
#include <hip/hip_runtime.h>

// Depthwise 5x5 SAME conv + gate residual: out = x*(alpha*conv + bias) + x
// x: (B=32, H=112, W=112, C=96) f32 NHWC. kernel: (5,5,96) f32.
//
// R9: WALK ALONG W (contiguous axis), not H. All prior rounds (R1-R8)
// walked H: every wave's consecutive requests were 43 KB apart -> ~5000
// short DRAM streams chip-wide -> effective BW pinned at 2-2.9 TB/s no
// matter the structure. Here each thread owns (b, h, c2) and slides along
// w: its 5 vertical taps (rows h-2..h+2) and its store advance LINEARLY
// at 384 B/step -> 6 linear DRAM streams per thread, page-friendly.
//  - H-edge: thread-constant -> fold into weight-zeroing (zero invalid dy
//    rows once); tap row pointers clamped. No per-body masking.
//  - W-edge: wave-uniform branch, taken on 4 of 60 bodies only.
//  - Ring accumulator over w (acc[j] = partial for output w_cur-2+j),
//    center-tap delay-2 recycled for the residual. Same math as R1,
//    axes swapped.
//  - Block 192 thr = 48 c2 x 4 h-rows: in-block (hsub,dy) overlap -> L1
//    broadcast; x (154 MB) fits L3 so cross-block row re-reads stay on-die.
//  - NSPLITW=2 (w 0..55 | 56..111): 60 bodies serial depth, 5376 waves.

#define CHN   96
#define C2    48                 // float2 channel pairs
#define WI    112
#define HI    112
#define NB    32
#define HPB   4                  // h rows per block
#define NHB   (HI / HPB)         // 28
#define NSW   2                  // w chunks
#define WC    (WI / NSW)         // 56 outputs per chunk
#define NTHR  192                // 3 waves = 48 c2 x 4 h
#define GROW  (WI * C2)          // f2 per (b,h) row = 5376
#define GIMG  (HI * GROW)

__global__ __launch_bounds__(NTHR) void dwconv_gate_wwalk(
    const float* __restrict__ xf,
    const float* __restrict__ kf,
    const float* __restrict__ alpha,
    const float* __restrict__ bias,
    float* __restrict__ of)
{
    const int tid  = threadIdx.x;
    const int c2l  = tid % C2;
    const int hsub = tid / C2;                 // 0..3
    const int bid  = blockIdx.x;
    const int wch  = bid % NSW;
    const int hg   = (bid / NSW) % NHB;
    const int b    = bid / (NSW * NHB);

    const int h  = hg * HPB + hsub;            // this thread's output row
    const int w0 = wch * WC;

    const float av = alpha[0];
    const float bv = bias[0];
    const float2 z2 = make_float2(0.f, 0.f);

    // Weights: zero the dy-rows whose input row h-2+dy is out of range
    // (thread-constant). Tap pointers are clamped, so loads stay valid and
    // the zeroed weights kill the contribution.
    float2 wt[25];
#pragma unroll
    for (int dy = 0; dy < 5; ++dy) {
        const int hin = h - 2 + dy;
        const bool ok = (hin >= 0) && (hin < HI);
#pragma unroll
        for (int dx = 0; dx < 5; ++dx) {
            float2 v = *(const float2*)(kf + (dy * 5 + dx) * CHN + 2 * c2l);
            wt[dy * 5 + dx] = ok ? v : z2;
        }
    }

    const float2* gx = (const float2*)xf + (size_t)b * GIMG;
    float2*       go = (float2*)of       + (size_t)b * GIMG;

    // Clamped row base pointers, pre-offset to column (w0-2), advanced by
    // C2 every body. Negative start offset is pointer arithmetic only; the
    // uniform w-branch skips dereferencing while out of range.
    const int r0 = (h - 2 < 0) ? 0 : h - 2;
    const int r1 = (h - 1 < 0) ? 0 : h - 1;
    const int r2 = h;
    const int r3 = (h + 1 >= HI) ? HI - 1 : h + 1;
    const int r4 = (h + 2 >= HI) ? HI - 1 : h + 2;
    const float2* p0 = gx + (size_t)r0 * GROW + (ptrdiff_t)(w0 - 2) * C2 + c2l;
    const float2* p1 = gx + (size_t)r1 * GROW + (ptrdiff_t)(w0 - 2) * C2 + c2l;
    const float2* p2 = gx + (size_t)r2 * GROW + (ptrdiff_t)(w0 - 2) * C2 + c2l;
    const float2* p3 = gx + (size_t)r3 * GROW + (ptrdiff_t)(w0 - 2) * C2 + c2l;
    const float2* p4 = gx + (size_t)r4 * GROW + (ptrdiff_t)(w0 - 2) * C2 + c2l;
    float2* po = go + (size_t)h * GROW + (ptrdiff_t)(w0 - 4) * C2 + c2l;

    // acc[j]: partial sum for output column (w_cur - 2 + j).
    float2 acc0 = z2, acc1 = z2, acc2 = z2, acc3 = z2, acc4 = z2;
    float2 xp1 = z2, xp2 = z2;     // center-row tap history (delay 2)

    for (int i = 0; i < WC + 4; ++i) {
        const int wcur = w0 - 2 + i;

        // 5 vertical taps at column wcur (wave-uniform validity branch;
        // only bodies 0,1 and the last 2 of the edge chunks take else).
        float2 t0, t1, t2, t3, t4;
        if ((unsigned)wcur < (unsigned)WI) {
            t0 = *p0; t1 = *p1; t2 = *p2; t3 = *p3; t4 = *p4;
        } else {
            t0 = z2; t1 = z2; t2 = z2; t3 = z2; t4 = z2;
        }
        p0 += C2; p1 += C2; p2 += C2; p3 += C2; p4 += C2;

        // Column wcur feeds output w' = wcur-2+j with kernel dx = 4-j.
#pragma unroll
        for (int j = 0; j < 5; ++j) {
            const int dxk = 4 - j;
            float2* a = (j == 0) ? &acc0 : (j == 1) ? &acc1 :
                        (j == 2) ? &acc2 : (j == 3) ? &acc3 : &acc4;
            a->x = fmaf(t0.x, wt[ 0 + dxk].x, a->x);
            a->y = fmaf(t0.y, wt[ 0 + dxk].y, a->y);
            a->x = fmaf(t1.x, wt[ 5 + dxk].x, a->x);
            a->y = fmaf(t1.y, wt[ 5 + dxk].y, a->y);
            a->x = fmaf(t2.x, wt[10 + dxk].x, a->x);
            a->y = fmaf(t2.y, wt[10 + dxk].y, a->y);
            a->x = fmaf(t3.x, wt[15 + dxk].x, a->x);
            a->y = fmaf(t3.y, wt[15 + dxk].y, a->y);
            a->x = fmaf(t4.x, wt[20 + dxk].x, a->x);
            a->y = fmaf(t4.y, wt[20 + dxk].y, a->y);
        }

        // Emit output column w' = w0-4+i once its 5-column window closed.
        if (i >= 4) {
            float2 o;
            o.x = fmaf(fmaf(acc0.x, av, bv), xp2.x, xp2.x);
            o.y = fmaf(fmaf(acc0.y, av, bv), xp2.y, xp2.y);
            po[(ptrdiff_t)i * C2] = o;
        }

        xp2 = xp1; xp1 = t2;
        acc0 = acc1; acc1 = acc2; acc2 = acc3; acc3 = acc4; acc4 = z2;
    }
}

extern "C" void kernel_launch(void* const* d_in, const int* in_sizes, int n_in,
                              void* d_out, int out_size, void* d_ws, size_t ws_size,
                              hipStream_t stream) {
    const float* x     = (const float*)d_in[0];
    const float* kern  = (const float*)d_in[1];
    const float* alpha = (const float*)d_in[2];
    const float* bias  = (const float*)d_in[3];
    float* out = (float*)d_out;

    dim3 block(NTHR);
    dim3 grid(NB * NHB * NSW);     // 32*28*2 = 1792 blocks, 5376 waves
    hipLaunchKernelGGL(dwconv_gate_wwalk, grid, block, 0, stream,
                       x, kern, alpha, bias, out);
}